// Round 10
// baseline (126.478 us; speedup 1.0000x reference)
//
#include <hip/hip_runtime.h>
#include <math.h>

#define PAD_IDX 0
#define BIGV 10000.0f
constexpr int B_ = 1024, S_ = 128, V_ = 200, E_ = 512, H_ = 512, T_ = 24;

// ws layout (float offsets):
//   w1Tb   [512][512] bf16 @ 0      (w1 transposed+bf16: w1Tb[k][t] = bf16(w1[t][k]))
//   h_ws   [200][512]  @ 262144
//   em_tab [200][24]   @ 364544
//   w_tab  [200][24]   @ 369344
//   emax   [200]       @ 374144
constexpr int OFF_H  = 262144;
constexpr int OFF_EM = 364544;
constexpr int OFF_W  = 369344;
constexpr int OFF_MX = 374144;

__device__ __forceinline__ unsigned short f2bf(float f) {
    unsigned u = __float_as_uint(f);
    u += 0x7fffu + ((u >> 16) & 1u);      // round-to-nearest-even
    return (unsigned short)(u >> 16);
}

// ---------------------------------------------------------------------------
// Kernel T: transpose w1 (512x512) -> bf16 via 64x64 LDS tiles (+1 pad).
// Also zero-inits out[0] for crf's atomics.
// ---------------------------------------------------------------------------
__global__ __launch_bounds__(256) void transpose_kernel(
    const float* __restrict__ w1, unsigned short* __restrict__ w1Tb,
    float* __restrict__ out)
{
    __shared__ float tile[64][65];
    const int bi = blockIdx.x >> 3, bj = blockIdx.x & 7;
    const int tx = threadIdx.x & 63, r0 = (threadIdx.x >> 6) * 16;
    if (blockIdx.x == 0 && threadIdx.x == 0) out[0] = 0.f;
    #pragma unroll
    for (int m = 0; m < 16; ++m) {
        const int r = r0 + m;
        tile[r][tx] = w1[(size_t)(bi * 64 + r) * 512 + bj * 64 + tx];
    }
    __syncthreads();
    #pragma unroll
    for (int m = 0; m < 16; ++m) {
        const int r = r0 + m;
        w1Tb[(size_t)(bj * 64 + r) * 512 + bi * 64 + tx] = f2bf(tile[tx][r]);
    }
}

// ---------------------------------------------------------------------------
// Kernel A1: h_ws[v][t] = relu(emb[v].w1[t] + b1[t]) (unchanged from R9).
// ---------------------------------------------------------------------------
__global__ __launch_bounds__(256) void h_kernel(
    const float* __restrict__ emb, const unsigned short* __restrict__ w1Tb,
    const float* __restrict__ b1, float* __restrict__ h_ws)
{
    __shared__ float xi[2 * E_];           // interleaved {x0[k], x1[k]}
    __shared__ float part_s[4][64][8];     // [k-part][t-quad][4t x 2v]
    const int pair = blockIdx.x >> 1, half = blockIdx.x & 1;
    const int v0 = pair * 2, v1 = v0 + 1;
    const int tid = threadIdx.x;

    {
        const float* __restrict__ x0 = emb + (size_t)v0 * E_;
        const float* __restrict__ x1 = emb + (size_t)v1 * E_;
        #pragma unroll
        for (int m = 0; m < 2; ++m) {
            const int k = tid + m * 256;
            xi[2 * k]     = x0[k];
            xi[2 * k + 1] = x1[k];
        }
    }
    __syncthreads();

    const int part = tid >> 6;
    const int quad = tid & 63;
    const int t0 = half * 256 + quad * 4;
    const int k0 = part * 128;

    float a0 = 0.f, a1 = 0.f, a2 = 0.f, a3 = 0.f;
    float c0 = 0.f, c1 = 0.f, c2 = 0.f, c3 = 0.f;
    const unsigned short* __restrict__ wp = w1Tb + (size_t)k0 * H_ + t0;
    const float2* __restrict__ xp = (const float2*)xi + k0;
    #pragma unroll 4
    for (int i = 0; i < 128; ++i) {
        const uint2 wu = *(const uint2*)(wp + (size_t)i * H_);
        const float2 x = xp[i];
        const float w0 = __uint_as_float(wu.x << 16);
        const float w1v = __uint_as_float(wu.x & 0xffff0000u);
        const float w2v = __uint_as_float(wu.y << 16);
        const float w3v = __uint_as_float(wu.y & 0xffff0000u);
        a0 = fmaf(w0,  x.x, a0); a1 = fmaf(w1v, x.x, a1);
        a2 = fmaf(w2v, x.x, a2); a3 = fmaf(w3v, x.x, a3);
        c0 = fmaf(w0,  x.y, c0); c1 = fmaf(w1v, x.y, c1);
        c2 = fmaf(w2v, x.y, c2); c3 = fmaf(w3v, x.y, c3);
    }
    part_s[part][quad][0] = a0; part_s[part][quad][1] = a1;
    part_s[part][quad][2] = a2; part_s[part][quad][3] = a3;
    part_s[part][quad][4] = c0; part_s[part][quad][5] = c1;
    part_s[part][quad][6] = c2; part_s[part][quad][7] = c3;
    __syncthreads();

    {
        const int q2 = tid >> 2, r0 = tid & 3;
        const float s0 = (part_s[0][q2][r0]     + part_s[1][q2][r0])
                       + (part_s[2][q2][r0]     + part_s[3][q2][r0]);
        const float s1 = (part_s[0][q2][r0 + 4] + part_s[1][q2][r0 + 4])
                       + (part_s[2][q2][r0 + 4] + part_s[3][q2][r0 + 4]);
        const int t = half * 256 + tid;
        const float bb = b1[t];
        h_ws[(size_t)v0 * H_ + t] = fmaxf(s0 + bb, 0.f);
        h_ws[(size_t)v1 * H_ + t] = fmaxf(s1 + bb, 0.f);
    }
}

// ---------------------------------------------------------------------------
// Kernel A2: em_table / w_table / emax (unchanged from R9).
// ---------------------------------------------------------------------------
__global__ __launch_bounds__(256) void emis_kernel(
    const float* __restrict__ h_ws, const float* __restrict__ w2,
    const float* __restrict__ b2, float* __restrict__ em_table,
    float* __restrict__ w_table, float* __restrict__ emax_arr)
{
    __shared__ float em_row[32];
    const int v = blockIdx.x;
    const int t = threadIdx.x;
    const int wave = t >> 6, lane = t & 63;
    const float* __restrict__ hrow = h_ws + (size_t)v * H_;

    for (int jj2 = 0; jj2 < 6; ++jj2) {
        const int jo = wave * 6 + jj2;
        float part = 0.f;
        #pragma unroll
        for (int m = 0; m < H_ / 64; ++m) {
            const int k = lane + m * 64;
            part = fmaf(hrow[k], w2[(size_t)jo * H_ + k], part);
        }
        #pragma unroll
        for (int off = 32; off; off >>= 1)
            part += __shfl_xor(part, off, 64);
        if (lane == 0) {
            float val = fmaxf(part + b2[jo], 0.f);
            if (v == 0 && jo == PAD_IDX) val += BIGV;  // pad boost baked in
            em_row[jo] = val;
        }
    }
    __syncthreads();

    if (t < 32) {
        float x = (t < T_) ? em_row[t] : -INFINITY;
        float mx = x;
        #pragma unroll
        for (int off = 16; off; off >>= 1)
            mx = fmaxf(mx, __shfl_xor(mx, off, 32));
        if (t < T_) {
            em_table[v * T_ + t] = x;
            w_table[v * T_ + t]  = __expf(x - mx);
        }
        if (t == 0) emax_arr[v] = mx;
    }
}

// ---------------------------------------------------------------------------
// Kernel B: CRF fwd/bwd meet-in-middle (R10 = R9 math, VALU broadcasts).
// R9 post-mortem: 24 ds_swizzle/step issue on the per-CU LDS pipe shared by
// all 4 resident waves -> DS-throughput-bound (~30us). R10: broadcasts via
// v_readlane (compile-time lane) -> wave-uniform SGPR feeding v_fma's one
// allowed SGPR operand. 48 readlane + 48 fma per step, all on the per-SIMD
// VALU pipe (scales with waves); DS reduced to the per-step wv gather.
// Per-half coef arrays EF (E-col, fwd lanes) / EB (E-row, bwd lanes) are
// zero on the other half's lanes -> math identical to R9 (absmax was 0.0).
// ---------------------------------------------------------------------------
#define RL(i) __uint_as_float(__builtin_amdgcn_readlane(qi, (i)))
#define ACCRL(base)                                        \
    s0 = fmaf(RL((base)),      EF[(base)],     s0);        \
    s1 = fmaf(RL((base) + 1),  EF[(base) + 1], s1);        \
    s2 = fmaf(RL((base) + 2),  EF[(base) + 2], s2);        \
    s3 = fmaf(RL((base) + 3),  EF[(base) + 3], s3);        \
    s0 = fmaf(RL((base) + 32), EB[(base)],     s0);        \
    s1 = fmaf(RL((base) + 33), EB[(base) + 1], s1);        \
    s2 = fmaf(RL((base) + 34), EB[(base) + 2], s2);        \
    s3 = fmaf(RL((base) + 35), EB[(base) + 3], s3);

__global__ __launch_bounds__(256) void crf_kernel(
    const int* __restrict__ seq, const int* __restrict__ labels,
    const float* __restrict__ start_t, const float* __restrict__ end_t,
    const float* __restrict__ trans, const float* __restrict__ em_table,
    const float* __restrict__ w_table, const float* __restrict__ emax_arr,
    float* __restrict__ out)
{
    __shared__ __align__(16) float w_s[V_ * T_];
    __shared__ float emax_s[V_];
    __shared__ int   tok_s[4 * S_];
    const int tid = threadIdx.x;
    {
        const float4* __restrict__ src = (const float4*)w_table;
        float4* dst = (float4*)w_s;
        for (int i = tid; i < V_ * T_ / 4; i += 256) dst[i] = src[i];
    }
    for (int i = tid; i < V_; i += 256) emax_s[i] = emax_arr[i];
    {
        const int base = blockIdx.x * 4 * S_;
        #pragma unroll
        for (int i = 0; i < 2; ++i)
            tok_s[tid + i * 256] = seq[base + tid + i * 256];
    }
    __syncthreads();

    const int wave = tid >> 6, lane = tid & 63;
    const int b = blockIdx.x * 4 + wave;
    const int jl = lane & 31;
    const int jj = (jl < T_) ? jl : 0;
    const bool act = (jl < T_);
    const bool isF = (lane < 32);
    const int* __restrict__ lrow = labels + (size_t)b * S_;
    const int* __restrict__ tks  = tok_s + wave * S_;

    // EF: fwd lane j -> E[i][j] (column), zero on bwd lanes.
    // EB: bwd lane j -> E[j][i] (row),    zero on fwd lanes.
    float EF[T_], EB[T_];
    #pragma unroll
    for (int i = 0; i < T_; ++i) {
        EF[i] = (act && isF)  ? __expf(trans[i * T_ + jj]) : 0.f;
        EB[i] = (act && !isF) ? __expf(trans[jj * T_ + i]) : 0.f;
    }

    // init both chains (unified, per-lane selects)
    const int tokI = isF ? tks[0] : tks[S_ - 1];
    const float bse = isF ? start_t[jj] : end_t[jj];
    const float a0v = bse + em_table[tokI * T_ + jj];
    float m0 = act ? a0v : -INFINITY;
    #pragma unroll
    for (int off = 16; off; off >>= 1)
        m0 = fmaxf(m0, __shfl_xor(m0, off, 32));
    const float qFi = __expf(a0v - m0);                    // fwd init
    const float qBi = w_s[tokI * T_ + jj] * __expf(bse);   // bwd init (b_0)
    float q = act ? (isF ? qFi : qBi) : 0.f;
    float logacc = isF ? m0 : 0.f;

    // per-lane token index direction: idx(i) = off_l + dir_l * i
    const int dir_l = isF ? 1 : -1;
    const int off_l = isF ? 0 : 127;

    // software pipeline: wv = W for step 1; tokN = token for step 2
    float wv = w_s[tks[off_l + dir_l] * T_ + jj];
    int tokN = tks[off_l + dir_l * 2];

    for (int s = 1; s <= 63; ++s) {
        const float wn = w_s[tokN * T_ + jj];          // W for step s+1
        const int nxt = (s + 2 <= 63) ? s + 2 : 63;
        const int tokC = tks[off_l + dir_l * nxt];
        const unsigned qi = __float_as_uint(q);
        float s0 = 0.f, s1 = 0.f, s2 = 0.f, s3 = 0.f;
        ACCRL(0) ACCRL(4) ACCRL(8) ACCRL(12) ACCRL(16) ACCRL(20)
        q = ((s0 + s1) + (s2 + s3)) * wv;
        wv = wn; tokN = tokC;
        if ((s & 15) == 0) {                           // renorm every 16 steps
            float m = q;
            #pragma unroll
            for (int off = 16; off; off >>= 1)
                m = fmaxf(m, __shfl_xor(m, off, 32));
            q *= (1.0f / m);
            logacc += __logf(m);
        }
    }
    // fwd lanes hold A_63; bwd lanes hold b_63 (= W_64 (.) P_64).

    // final renorm of BOTH halves before the meet (R9 overflow fix).
    {
        float m = q;
        #pragma unroll
        for (int off = 16; off; off >>= 1)
            m = fmaxf(m, __shfl_xor(m, off, 32));
        q *= (1.0f / m);
        logacc += __logf(m);
    }

    // half-step (no W): u = sum_i q[i]*Ecoef[i]  (useful on fwd lanes)
    float u;
    {
        const unsigned qi = __float_as_uint(q);
        float s0 = 0.f, s1 = 0.f, s2 = 0.f, s3 = 0.f;
        ACCRL(0) ACCRL(4) ACCRL(8) ACCRL(12) ACCRL(16) ACCRL(20)
        u = (s0 + s1) + (s2 + s3);
    }

    // cross-half dot: sel = u (fwd) / b_63 (bwd); each product counted twice.
    const float sel = isF ? u : q;
    const float oth = __shfl_xor(sel, 32, 64);
    float prod = sel * oth;
    #pragma unroll
    for (int off = 32; off; off >>= 1)
        prod += __shfl_xor(prod, off, 64);
    const float logacc_o = __shfl_xor(logacc, 32, 64);
    const float denom = logacc + logacc_o + __logf(0.5f * prod);

    // gold path: lane handles steps lane and lane+64 (minus Sum_{s>=1} emax)
    float gp = 0.f;
    #pragma unroll
    for (int r = 0; r < 2; ++r) {
        const int s = lane + r * 64;
        const int tk = tks[s];
        const int ls = lrow[s];
        gp += em_table[tk * T_ + ls];
        if (s >= 1) gp -= emax_s[tk];
        if (s < S_ - 1) gp += trans[ls * T_ + lrow[s + 1]];
        if (s == 0) gp += start_t[ls];
        if (s == S_ - 1) gp += end_t[ls];
    }
    #pragma unroll
    for (int off = 32; off; off >>= 1)
        gp += __shfl_xor(gp, off, 64);

    if (lane == 0)
        atomicAdd(out, (denom - gp) * (1.0f / (float)B_));
}

// ---------------------------------------------------------------------------
extern "C" void kernel_launch(void* const* d_in, const int* in_sizes, int n_in,
                              void* d_out, int out_size, void* d_ws, size_t ws_size,
                              hipStream_t stream) {
    const int*   seq     = (const int*)d_in[0];
    const int*   labels  = (const int*)d_in[1];
    // d_in[2] true_lengths: unused by the reference forward
    const float* emb     = (const float*)d_in[3];
    const float* w1      = (const float*)d_in[4];
    const float* b1      = (const float*)d_in[5];
    const float* w2      = (const float*)d_in[6];
    const float* b2      = (const float*)d_in[7];
    const float* start_t = (const float*)d_in[8];
    const float* end_t   = (const float*)d_in[9];
    const float* trans   = (const float*)d_in[10];

    float* ws       = (float*)d_ws;
    unsigned short* w1Tb = (unsigned short*)d_ws;
    float* h_ws     = ws + OFF_H;
    float* em_table = ws + OFF_EM;
    float* w_table  = ws + OFF_W;
    float* emax_arr = ws + OFF_MX;
    float* out      = (float*)d_out;

    transpose_kernel<<<64, 256, 0, stream>>>(w1, w1Tb, out);
    h_kernel<<<200, 256, 0, stream>>>(emb, w1Tb, b1, h_ws);
    emis_kernel<<<V_, 256, 0, stream>>>(h_ws, w2, b2, em_table, w_table, emax_arr);
    crf_kernel<<<B_ / 4, 256, 0, stream>>>(seq, labels, start_t, end_t, trans,
                                           em_table, w_table, emax_arr, out);
}

// Round 11
// 119.560 us; speedup vs baseline: 1.0579x; 1.0579x over previous
//
#include <hip/hip_runtime.h>
#include <math.h>

#define PAD_IDX 0
#define BIGV 10000.0f
constexpr int B_ = 1024, S_ = 128, V_ = 200, E_ = 512, H_ = 512, T_ = 24;

// ws layout (float offsets):
constexpr int OFF_H  = 262144;   // h_ws   [200][512]
constexpr int OFF_EM = 364544;   // em_tab [200][24]
constexpr int OFF_W  = 369344;   // w_tab  [200][24]
constexpr int OFF_MX = 374144;   // emax   [200]
constexpr int OFF_GP = 374344;   // gp_ws  [1024]

typedef __attribute__((ext_vector_type(8)))  short    bf8frag;   // 8 bf16 (4 VGPRs)
typedef __attribute__((ext_vector_type(16))) float    facc16;    // MFMA C/D
typedef __attribute__((ext_vector_type(4)))  unsigned u32x4;

__device__ __forceinline__ unsigned short f2bf(float f) {
    unsigned u = __float_as_uint(f);
    u += 0x7fffu + ((u >> 16) & 1u);      // RNE
    return (unsigned short)(u >> 16);
}
// pack 2 fp32 -> 2 bf16 (round-half-up; q >= 0 always here)
__device__ __forceinline__ unsigned pkbf(float lo, float hi) {
    const unsigned a = __float_as_uint(lo), b = __float_as_uint(hi);
    return ((a + 0x8000u) >> 16) | ((b + 0x8000u) & 0xffff0000u);
}

// ---------------------------------------------------------------------------
// Kernel T: transpose w1 -> bf16 (unchanged, proven). Zeroes out[0].
// ---------------------------------------------------------------------------
__global__ __launch_bounds__(256) void transpose_kernel(
    const float* __restrict__ w1, unsigned short* __restrict__ w1Tb,
    float* __restrict__ out)
{
    __shared__ float tile[64][65];
    const int bi = blockIdx.x >> 3, bj = blockIdx.x & 7;
    const int tx = threadIdx.x & 63, r0 = (threadIdx.x >> 6) * 16;
    if (blockIdx.x == 0 && threadIdx.x == 0) out[0] = 0.f;
    #pragma unroll
    for (int m = 0; m < 16; ++m) {
        const int r = r0 + m;
        tile[r][tx] = w1[(size_t)(bi * 64 + r) * 512 + bj * 64 + tx];
    }
    __syncthreads();
    #pragma unroll
    for (int m = 0; m < 16; ++m) {
        const int r = r0 + m;
        w1Tb[(size_t)(bj * 64 + r) * 512 + bi * 64 + tx] = f2bf(tile[tx][r]);
    }
}

// ---------------------------------------------------------------------------
// Kernel A1: h_ws (unchanged, proven).
// ---------------------------------------------------------------------------
__global__ __launch_bounds__(256) void h_kernel(
    const float* __restrict__ emb, const unsigned short* __restrict__ w1Tb,
    const float* __restrict__ b1, float* __restrict__ h_ws)
{
    __shared__ float xi[2 * E_];
    __shared__ float part_s[4][64][8];
    const int pair = blockIdx.x >> 1, half = blockIdx.x & 1;
    const int v0 = pair * 2, v1 = v0 + 1;
    const int tid = threadIdx.x;
    {
        const float* __restrict__ x0 = emb + (size_t)v0 * E_;
        const float* __restrict__ x1 = emb + (size_t)v1 * E_;
        #pragma unroll
        for (int m = 0; m < 2; ++m) {
            const int k = tid + m * 256;
            xi[2 * k]     = x0[k];
            xi[2 * k + 1] = x1[k];
        }
    }
    __syncthreads();
    const int part = tid >> 6, quad = tid & 63;
    const int t0 = half * 256 + quad * 4, k0 = part * 128;
    float a0 = 0.f, a1 = 0.f, a2 = 0.f, a3 = 0.f;
    float c0 = 0.f, c1 = 0.f, c2 = 0.f, c3 = 0.f;
    const unsigned short* __restrict__ wp = w1Tb + (size_t)k0 * H_ + t0;
    const float2* __restrict__ xp = (const float2*)xi + k0;
    #pragma unroll 4
    for (int i = 0; i < 128; ++i) {
        const uint2 wu = *(const uint2*)(wp + (size_t)i * H_);
        const float2 x = xp[i];
        const float w0 = __uint_as_float(wu.x << 16);
        const float w1v = __uint_as_float(wu.x & 0xffff0000u);
        const float w2v = __uint_as_float(wu.y << 16);
        const float w3v = __uint_as_float(wu.y & 0xffff0000u);
        a0 = fmaf(w0,  x.x, a0); a1 = fmaf(w1v, x.x, a1);
        a2 = fmaf(w2v, x.x, a2); a3 = fmaf(w3v, x.x, a3);
        c0 = fmaf(w0,  x.y, c0); c1 = fmaf(w1v, x.y, c1);
        c2 = fmaf(w2v, x.y, c2); c3 = fmaf(w3v, x.y, c3);
    }
    part_s[part][quad][0] = a0; part_s[part][quad][1] = a1;
    part_s[part][quad][2] = a2; part_s[part][quad][3] = a3;
    part_s[part][quad][4] = c0; part_s[part][quad][5] = c1;
    part_s[part][quad][6] = c2; part_s[part][quad][7] = c3;
    __syncthreads();
    {
        const int q2 = tid >> 2, r0 = tid & 3;
        const float s0 = (part_s[0][q2][r0]     + part_s[1][q2][r0])
                       + (part_s[2][q2][r0]     + part_s[3][q2][r0]);
        const float s1 = (part_s[0][q2][r0 + 4] + part_s[1][q2][r0 + 4])
                       + (part_s[2][q2][r0 + 4] + part_s[3][q2][r0 + 4]);
        const int t = half * 256 + tid;
        const float bb = b1[t];
        h_ws[(size_t)v0 * H_ + t] = fmaxf(s0 + bb, 0.f);
        h_ws[(size_t)v1 * H_ + t] = fmaxf(s1 + bb, 0.f);
    }
}

// ---------------------------------------------------------------------------
// Kernel A2: em_table / w_table / emax (unchanged, proven).
// ---------------------------------------------------------------------------
__global__ __launch_bounds__(256) void emis_kernel(
    const float* __restrict__ h_ws, const float* __restrict__ w2,
    const float* __restrict__ b2, float* __restrict__ em_table,
    float* __restrict__ w_table, float* __restrict__ emax_arr)
{
    __shared__ float em_row[32];
    const int v = blockIdx.x;
    const int t = threadIdx.x;
    const int wave = t >> 6, lane = t & 63;
    const float* __restrict__ hrow = h_ws + (size_t)v * H_;
    for (int jj2 = 0; jj2 < 6; ++jj2) {
        const int jo = wave * 6 + jj2;
        float part = 0.f;
        #pragma unroll
        for (int m = 0; m < H_ / 64; ++m) {
            const int k = lane + m * 64;
            part = fmaf(hrow[k], w2[(size_t)jo * H_ + k], part);
        }
        #pragma unroll
        for (int off = 32; off; off >>= 1)
            part += __shfl_xor(part, off, 64);
        if (lane == 0) {
            float val = fmaxf(part + b2[jo], 0.f);
            if (v == 0 && jo == PAD_IDX) val += BIGV;
            em_row[jo] = val;
        }
    }
    __syncthreads();
    if (t < 32) {
        float x = (t < T_) ? em_row[t] : -INFINITY;
        float mx = x;
        #pragma unroll
        for (int off = 16; off; off >>= 1)
            mx = fmaxf(mx, __shfl_xor(mx, off, 32));
        if (t < T_) {
            em_table[v * T_ + t] = x;
            w_table[v * T_ + t]  = __expf(x - mx);
        }
        if (t == 0) emax_arr[v] = mx;
    }
}

// ---------------------------------------------------------------------------
// Kernel G: gold-path scores (exact R9 math, hoisted out of crf).
// gp_ws[b] = gold score - Sum_{s>=1} emax[tok_s]. 8 batches/block.
// ---------------------------------------------------------------------------
__global__ __launch_bounds__(256) void gold_kernel(
    const int* __restrict__ seq, const int* __restrict__ labels,
    const float* __restrict__ start_t, const float* __restrict__ end_t,
    const float* __restrict__ trans, const float* __restrict__ em_table,
    const float* __restrict__ emax_arr, float* __restrict__ gp_ws)
{
    const int grp = threadIdx.x >> 5, j = threadIdx.x & 31;
    const int b = blockIdx.x * 8 + grp;
    const int* __restrict__ srow = seq + (size_t)b * S_;
    const int* __restrict__ lrow = labels + (size_t)b * S_;
    float gp = 0.f;
    #pragma unroll
    for (int r = 0; r < 4; ++r) {
        const int s = j + r * 32;
        const int tk = srow[s], ls = lrow[s];
        gp += em_table[tk * T_ + ls];
        if (s >= 1) gp -= emax_arr[tk];
        if (s < S_ - 1) gp += trans[ls * T_ + lrow[s + 1]];
        if (s == 0) gp += start_t[ls];
        if (s == S_ - 1) gp += end_t[ls];
    }
    #pragma unroll
    for (int off = 16; off; off >>= 1)
        gp += __shfl_xor(gp, off, 32);
    if (j == 0) gp_ws[b] = gp;
}

// ---------------------------------------------------------------------------
// Kernel B: CRF meet-in-middle on the MATRIX pipe (R11).
// One block = one 32-batch group: wave0 = fwd chains, wave1 = bwd chains.
// Per step (32 batches at once): Q' = (E^{T or } Q) (.) W via
// v_mfma_f32_32x32x16_bf16 pair (K=24 = 16+8, A loop-invariant bf16).
// C/D layout (verified m74/m101): col=lane&31 (batch), row=(reg&3)+8*(reg>>2)
// +4*(lane>>5). C->B relayout: 6 packs + 6 shfl_xor(32) + selects.
// W gathered from LDS (3 x ds_read_b128, prefetched 1 step ahead).
// Renorm every 16 steps + final (R9 overflow fix). Meet via LDS, denom
// combined with gp_ws, one atomicAdd per block.
// ---------------------------------------------------------------------------
__global__ __launch_bounds__(128) void crf_kernel(
    const int* __restrict__ seq,
    const float* __restrict__ start_t, const float* __restrict__ end_t,
    const float* __restrict__ trans, const float* __restrict__ em_table,
    const float* __restrict__ w_table, const float* __restrict__ gp_ws,
    float* __restrict__ out)
{
    __shared__ __align__(16) float w_s[V_ * T_];   // 19200 B
    __shared__ int   tok_s[S_ * 32];               // [s][n] transposed, 16384 B
    __shared__ float meet_s[64 * 12];
    __shared__ float logb_s[64];
    const int tid = threadIdx.x;
    const int g = blockIdx.x;

    for (int i = tid; i < V_ * T_ / 4; i += 128)
        ((float4*)w_s)[i] = ((const float4*)w_table)[i];
    {   // stage tokens transposed: tok_s[s][n] (bank = n, broadcast-friendly)
        const int bq = tid & 31, c = tid >> 5;
        const int* __restrict__ src = seq + (size_t)(g * 32 + bq) * S_ + c * 32;
        #pragma unroll 4
        for (int i = 0; i < 32; ++i)
            tok_s[(c * 32 + i) * 32 + bq] = src[i];
    }
    __syncthreads();

    const bool isF = (tid < 64);      // wave0 forward, wave1 backward
    const int lane = tid & 63;
    const int n = lane & 31;          // batch (B/D col) AND state row (A)
    const int h = lane >> 5;

    // A frags: fwd A[m][k]=E[k][m]; bwd A[m][k]=E[m][k]. k=8h+j (A1), 16+8h+j (A2).
    u32x4 A1p, A2p;
    {
        float a1e[8], a2e[8];
        #pragma unroll
        for (int j = 0; j < 8; ++j) {
            const int k1 = 8 * h + j;
            const int k2 = 16 + 8 * h + j;
            float v1 = 0.f, v2 = 0.f;
            if (n < T_) {
                v1 = __expf(isF ? trans[k1 * T_ + n] : trans[n * T_ + k1]);
                if (k2 < T_)
                    v2 = __expf(isF ? trans[k2 * T_ + n] : trans[n * T_ + k2]);
            }
            a1e[j] = v1; a2e[j] = v2;
        }
        #pragma unroll
        for (int r = 0; r < 4; ++r) {
            A1p[r] = pkbf(a1e[2 * r], a1e[2 * r + 1]);
            A2p[r] = pkbf(a2e[2 * r], a2e[2 * r + 1]);
        }
    }

    // init Q in B-layout: lane (n,h): B1 rows 8h..8h+7; B2 rows 16..23 (h==0).
    float logacc;
    u32x4 B1p, B2p;
    {
        const int tokI = tok_s[(isF ? 0 : (S_ - 1)) * 32 + n];
        float q1[8], q2[8];
        if (isF) {
            float e1[8], e2[8];
            #pragma unroll
            for (int j = 0; j < 8; ++j) { e1[j] = 0.f; e2[j] = 0.f; }
            float mx = -INFINITY;
            #pragma unroll
            for (int j = 0; j < 8; ++j) {
                const int r1 = 8 * h + j;
                e1[j] = start_t[r1] + em_table[tokI * T_ + r1];
                mx = fmaxf(mx, e1[j]);
            }
            if (h == 0) {
                #pragma unroll
                for (int j = 0; j < 8; ++j) {
                    const int r2 = 16 + j;
                    e2[j] = start_t[r2] + em_table[tokI * T_ + r2];
                    mx = fmaxf(mx, e2[j]);
                }
            }
            mx = fmaxf(mx, __shfl_xor(mx, 32, 64));
            #pragma unroll
            for (int j = 0; j < 8; ++j) {
                q1[j] = __expf(e1[j] - mx);
                q2[j] = (h == 0) ? __expf(e2[j] - mx) : 0.f;
            }
            logacc = mx;
        } else {
            #pragma unroll
            for (int j = 0; j < 8; ++j) {
                const int r1 = 8 * h + j;
                q1[j] = w_s[tokI * T_ + r1] * __expf(end_t[r1]);
                const int r2 = 16 + j;
                q2[j] = (h == 0) ? w_s[tokI * T_ + r2] * __expf(end_t[r2]) : 0.f;
            }
            logacc = 0.f;
        }
        #pragma unroll
        for (int r = 0; r < 4; ++r) {
            B1p[r] = pkbf(q1[2 * r], q1[2 * r + 1]);
            B2p[r] = pkbf(q2[2 * r], q2[2 * r + 1]);
        }
    }

    const int dir  = isF ? 1 : -1;
    const int offi = isF ? 1 : (S_ - 2);   // token idx for step s: offi + dir*(s-1)

    // W prefetch for step 1: rows {4h, 8+4h, 16+4h}+0..3 (matches D reg rows)
    float4 Wc0, Wc1, Wc2;
    {
        const int tk = tok_s[offi * 32 + n];
        const float* wb = w_s + tk * T_ + 4 * h;
        Wc0 = *(const float4*)(wb);
        Wc1 = *(const float4*)(wb + 8);
        Wc2 = *(const float4*)(wb + 16);
    }

    float d[12];
    for (int s = 1; s <= 63; ++s) {
        const int sn = (s < 63) ? (s + 1) : 63;
        const int tkN = tok_s[(offi + dir * (sn - 1)) * 32 + n];
        const float* wbn = w_s + tkN * T_ + 4 * h;
        const float4 Wn0 = *(const float4*)(wbn);
        const float4 Wn1 = *(const float4*)(wbn + 8);
        const float4 Wn2 = *(const float4*)(wbn + 16);

        facc16 acc;
        #pragma unroll
        for (int r = 0; r < 16; ++r) acc[r] = 0.f;
        acc = __builtin_amdgcn_mfma_f32_32x32x16_bf16(
                  __builtin_bit_cast(bf8frag, A2p),
                  __builtin_bit_cast(bf8frag, B2p), acc, 0, 0, 0);
        acc = __builtin_amdgcn_mfma_f32_32x32x16_bf16(
                  __builtin_bit_cast(bf8frag, A1p),
                  __builtin_bit_cast(bf8frag, B1p), acc, 0, 0, 0);

        d[0] = acc[0]*Wc0.x;  d[1] = acc[1]*Wc0.y;  d[2]  = acc[2]*Wc0.z;  d[3]  = acc[3]*Wc0.w;
        d[4] = acc[4]*Wc1.x;  d[5] = acc[5]*Wc1.y;  d[6]  = acc[6]*Wc1.z;  d[7]  = acc[7]*Wc1.w;
        d[8] = acc[8]*Wc2.x;  d[9] = acc[9]*Wc2.y;  d[10] = acc[10]*Wc2.z; d[11] = acc[11]*Wc2.w;

        if ((s & 15) == 0 || s == 63) {            // renorm + final (overflow fix)
            float mx = d[0];
            #pragma unroll
            for (int r = 1; r < 12; ++r) mx = fmaxf(mx, d[r]);
            mx = fmaxf(mx, __shfl_xor(mx, 32, 64));
            const float inv = 1.0f / mx;
            #pragma unroll
            for (int r = 0; r < 12; ++r) d[r] *= inv;
            logacc += __logf(mx);
        }

        // C -> B relayout: pack pairs, swap halves (row map per m74/m101)
        const unsigned P0 = pkbf(d[0], d[1]),  P1 = pkbf(d[2], d[3]);
        const unsigned P2 = pkbf(d[4], d[5]),  P3 = pkbf(d[6], d[7]);
        const unsigned P4 = pkbf(d[8], d[9]),  P5 = pkbf(d[10], d[11]);
        const unsigned XP0 = (unsigned)__shfl_xor((int)P0, 32, 64);
        const unsigned XP1 = (unsigned)__shfl_xor((int)P1, 32, 64);
        const unsigned XP2 = (unsigned)__shfl_xor((int)P2, 32, 64);
        const unsigned XP3 = (unsigned)__shfl_xor((int)P3, 32, 64);
        const unsigned XP4 = (unsigned)__shfl_xor((int)P4, 32, 64);
        const unsigned XP5 = (unsigned)__shfl_xor((int)P5, 32, 64);
        B1p[0] = h ? XP2 : P0;  B1p[1] = h ? XP3 : P1;
        B1p[2] = h ? P2  : XP0; B1p[3] = h ? P3  : XP1;
        B2p[0] = h ? 0u  : P4;  B2p[1] = h ? 0u  : P5;
        B2p[2] = h ? 0u  : XP4; B2p[3] = h ? 0u  : XP5;

        Wc0 = Wn0; Wc1 = Wn1; Wc2 = Wn2;
    }
    // fwd: d = alpha_63 (renormed), B frags = packed alpha_63.
    // bwd: d = b_64 (renormed).

    if (!isF) {
        #pragma unroll
        for (int r = 0; r < 12; ++r) meet_s[lane * 12 + r] = d[r];
        logb_s[lane] = logacc;
    }
    __syncthreads();
    if (isF) {
        // half-step U = E^T alpha_63 (no W), then dot with b_64 (same C-layout)
        facc16 acc;
        #pragma unroll
        for (int r = 0; r < 16; ++r) acc[r] = 0.f;
        acc = __builtin_amdgcn_mfma_f32_32x32x16_bf16(
                  __builtin_bit_cast(bf8frag, A2p),
                  __builtin_bit_cast(bf8frag, B2p), acc, 0, 0, 0);
        acc = __builtin_amdgcn_mfma_f32_32x32x16_bf16(
                  __builtin_bit_cast(bf8frag, A1p),
                  __builtin_bit_cast(bf8frag, B1p), acc, 0, 0, 0);
        float dot = 0.f;
        #pragma unroll
        for (int r = 0; r < 12; ++r)
            dot = fmaf(acc[r], meet_s[lane * 12 + r], dot);
        dot += __shfl_xor(dot, 32, 64);
        const float denom = logacc + logb_s[lane] + __logf(dot);
        float val = 0.f;
        if (h == 0)
            val = (denom - gp_ws[g * 32 + n]) * (1.0f / (float)B_);
        #pragma unroll
        for (int off = 32; off; off >>= 1)
            val += __shfl_xor(val, off, 64);
        if (lane == 0) atomicAdd(out, val);
    }
}

// ---------------------------------------------------------------------------
extern "C" void kernel_launch(void* const* d_in, const int* in_sizes, int n_in,
                              void* d_out, int out_size, void* d_ws, size_t ws_size,
                              hipStream_t stream) {
    const int*   seq     = (const int*)d_in[0];
    const int*   labels  = (const int*)d_in[1];
    // d_in[2] true_lengths: unused by the reference forward
    const float* emb     = (const float*)d_in[3];
    const float* w1      = (const float*)d_in[4];
    const float* b1      = (const float*)d_in[5];
    const float* w2      = (const float*)d_in[6];
    const float* b2      = (const float*)d_in[7];
    const float* start_t = (const float*)d_in[8];
    const float* end_t   = (const float*)d_in[9];
    const float* trans   = (const float*)d_in[10];

    float* ws       = (float*)d_ws;
    unsigned short* w1Tb = (unsigned short*)d_ws;
    float* h_ws     = ws + OFF_H;
    float* em_table = ws + OFF_EM;
    float* w_table  = ws + OFF_W;
    float* emax_arr = ws + OFF_MX;
    float* gp_ws    = ws + OFF_GP;
    float* out      = (float*)d_out;

    transpose_kernel<<<64, 256, 0, stream>>>(w1, w1Tb, out);
    h_kernel<<<200, 256, 0, stream>>>(emb, w1Tb, b1, h_ws);
    emis_kernel<<<V_, 256, 0, stream>>>(h_ws, w2, b2, em_table, w_table, emax_arr);
    gold_kernel<<<B_ / 8, 256, 0, stream>>>(seq, labels, start_t, end_t, trans,
                                            em_table, emax_arr, gp_ws);
    crf_kernel<<<B_ / 32, 128, 0, stream>>>(seq, start_t, end_t, trans,
                                            em_table, w_table, gp_ws, out);
}